// Round 11
// baseline (621.926 us; speedup 1.0000x reference)
//
#include <hip/hip_runtime.h>

#define NB 16    // N*G
#define CD 64    // C == Cv
#define HD 2048  // H

typedef unsigned short u16;
typedef __attribute__((ext_vector_type(8))) short s16x8;  // 8 bf16 (4 VGPRs)
typedef __attribute__((ext_vector_type(4))) float f32x4;  // MFMA C/D

__device__ __forceinline__ u16 f2bf(float x){
    unsigned u = __float_as_uint(x);
    u += 0x7FFFu + ((u >> 16) & 1u);   // RNE
    return (u16)(u >> 16);
}
__device__ __forceinline__ float bf2f(u16 h){ return __uint_as_float(((unsigned)h) << 16); }
__device__ __forceinline__ void split2(float x, u16& h, u16& l){
    h = f2bf(x); l = f2bf(x - bf2f(h));   // x - hi is exact in fp32
}
union Frag { uint4 q; s16x8 s; };
__device__ __forceinline__ s16x8 ld8(const u16* p){ Frag f; f.q = *(const uint4*)p; return f.s; }
__device__ __forceinline__ f32x4 mfma16(s16x8 a, s16x8 b, f32x4 c){
    return __builtin_amdgcn_mfma_f32_16x16x32_bf16(a, b, c, 0, 0, 0);
}
// fp32-emulating triple MFMA: hi*hi + hi*lo + lo*hi
__device__ __forceinline__ f32x4 mm3(s16x8 ah, s16x8 al, s16x8 bh, s16x8 bl, f32x4 c){
    c = mfma16(ah, bh, c);
    c = mfma16(ah, bl, c);
    c = mfma16(al, bh, c);
    return c;
}
__device__ __forceinline__ f32x4 z4(){ f32x4 v = {0.f,0.f,0.f,0.f}; return v; }

// ---------------- prep kernels (unchanged) ----------------

__global__ void k_convert(const float* __restrict__ src, u16* __restrict__ dh,
                          u16* __restrict__ dl, int n4)
{
    int idx = blockIdx.x*256 + threadIdx.x;
    if (idx >= n4) return;
    float4 v = ((const float4*)src)[idx];
    ushort4 h, l;
    split2(v.x, h.x, l.x); split2(v.y, h.y, l.y);
    split2(v.z, h.z, l.z); split2(v.w, h.w, l.w);
    ((ushort4*)dh)[idx] = h;
    ((ushort4*)dl)[idx] = l;
}

__global__ void k_transpose(const float* __restrict__ src, u16* __restrict__ dh,
                            u16* __restrict__ dl)
{
    int bg = blockIdx.y, h0 = blockIdx.x*128, tid = threadIdx.x;
    __shared__ float ft[CD][132];
    #pragma unroll
    for (int k=0;k<8;k++){
        int flat = tid + 256*k;
        int c = flat >> 5, p = (flat & 31)*4;
        *(float4*)&ft[c][p] = *(const float4*)(src + ((size_t)bg*CD + c)*HD + h0 + p);
    }
    __syncthreads();
    int hl = tid >> 1, c0 = (tid & 1)*32;
    union { u16 u[32]; uint4 q[4]; } oh, ol;
    #pragma unroll
    for (int m=0;m<32;m++){
        float x = ft[c0+m][hl];
        u16 hh; split2(x, hh, ol.u[m]); oh.u[m] = hh;
    }
    size_t base = ((size_t)bg*HD + h0 + hl)*CD + c0;
    #pragma unroll
    for (int t=0;t<4;t++){
        *((uint4*)(dh + base) + t) = oh.q[t];
        *((uint4*)(dl + base) + t) = ol.q[t];
    }
}

__global__ void k_bias(const float* __restrict__ mu, const float* __restrict__ beta,
                       float* __restrict__ bias)
{
    int bg = blockIdx.y;
    int j  = blockIdx.x*256 + threadIdx.x;
    const float* m = mu + (size_t)bg*CD*HD + j;
    float s = 0.f;
    #pragma unroll
    for (int c=0;c<CD;c++){ float v = m[(size_t)c*HD]; s = fmaf(v, v, s); }
    bias[(size_t)bg*HD + j] = 0.5f * beta[0] * s;
}

// ---------------- k_rowsum: proven r3 form (256,2), single r ----------------
__global__ __launch_bounds__(256,2) void k_rowsum(
    const u16* __restrict__ qTh, const u16* __restrict__ qTl,
    const u16* __restrict__ zTh, const u16* __restrict__ zTl,
    const float* __restrict__ bias, const float* __restrict__ alpha,
    float* __restrict__ r)
{
    const int bg = blockIdx.y, i0 = blockIdx.x*64;
    const int tid = threadIdx.x, wave = tid>>6, lane = tid&63, ln = lane&15, quad = lane>>4;
    const int jw = wave*32;
    const float a = alpha[0];
    __shared__ float rpart[4][64];

    s16x8 Ah[4][2], Al[4][2];     // resident q^T frags: rows i0..i0+63
    #pragma unroll
    for (int mt=0;mt<4;mt++)
        #pragma unroll
        for (int ks=0;ks<2;ks++){
            size_t off = ((size_t)bg*HD + i0 + mt*16 + ln)*CD + ks*32 + quad*8;
            Ah[mt][ks] = ld8(qTh + off);
            Al[mt][ks] = ld8(qTl + off);
        }
    float racc[16];
    #pragma unroll
    for (int k=0;k<16;k++) racc[k] = 0.f;
    const float* bb = bias + (size_t)bg*HD;

    s16x8 B0h[2][2], B0l[2][2], B1h[2][2], B1l[2][2];
    float bj0[2], bj1[2];

    // prologue: tile 0
    #pragma unroll
    for (int nt=0;nt<2;nt++){
        #pragma unroll
        for (int ks=0;ks<2;ks++){
            size_t off = ((size_t)bg*HD + jw + nt*16 + ln)*CD + ks*32 + quad*8;
            B0h[nt][ks] = ld8(zTh + off);
            B0l[nt][ks] = ld8(zTl + off);
        }
        bj0[nt] = bb[jw + nt*16 + ln];
    }

    for (int j0=0;j0<HD;j0+=256){
        #pragma unroll
        for (int nt=0;nt<2;nt++){
            #pragma unroll
            for (int ks=0;ks<2;ks++){
                size_t off = ((size_t)bg*HD + j0+128 + jw + nt*16 + ln)*CD + ks*32 + quad*8;
                B1h[nt][ks] = ld8(zTh + off);
                B1l[nt][ks] = ld8(zTl + off);
            }
            bj1[nt] = bb[j0+128 + jw + nt*16 + ln];
        }
        {
            f32x4 acc[4][2];
            #pragma unroll
            for (int mt=0;mt<4;mt++){ acc[mt][0]=z4(); acc[mt][1]=z4(); }
            #pragma unroll
            for (int ks=0;ks<2;ks++)
                #pragma unroll
                for (int mt=0;mt<4;mt++)
                    #pragma unroll
                    for (int nt=0;nt<2;nt++)
                        acc[mt][nt] = mm3(Ah[mt][ks], Al[mt][ks], B0h[nt][ks], B0l[nt][ks], acc[mt][nt]);
            #pragma unroll
            for (int mt=0;mt<4;mt++)
                #pragma unroll
                for (int nt=0;nt<2;nt++)
                    #pragma unroll
                    for (int rx=0;rx<4;rx++)
                        racc[mt*4+rx] += __expf(fmaf(a, acc[mt][nt][rx], bj0[nt]));
        }
        {
            int jn2 = (j0+256) & (HD-1);
            #pragma unroll
            for (int nt=0;nt<2;nt++){
                #pragma unroll
                for (int ks=0;ks<2;ks++){
                    size_t off = ((size_t)bg*HD + jn2 + jw + nt*16 + ln)*CD + ks*32 + quad*8;
                    B0h[nt][ks] = ld8(zTh + off);
                    B0l[nt][ks] = ld8(zTl + off);
                }
                bj0[nt] = bb[jn2 + jw + nt*16 + ln];
            }
        }
        {
            f32x4 acc[4][2];
            #pragma unroll
            for (int mt=0;mt<4;mt++){ acc[mt][0]=z4(); acc[mt][1]=z4(); }
            #pragma unroll
            for (int ks=0;ks<2;ks++)
                #pragma unroll
                for (int mt=0;mt<4;mt++)
                    #pragma unroll
                    for (int nt=0;nt<2;nt++)
                        acc[mt][nt] = mm3(Ah[mt][ks], Al[mt][ks], B1h[nt][ks], B1l[nt][ks], acc[mt][nt]);
            #pragma unroll
            for (int mt=0;mt<4;mt++)
                #pragma unroll
                for (int nt=0;nt<2;nt++)
                    #pragma unroll
                    for (int rx=0;rx<4;rx++)
                        racc[mt*4+rx] += __expf(fmaf(a, acc[mt][nt][rx], bj1[nt]));
        }
    }
    #pragma unroll
    for (int k=0;k<16;k++){
        float v = racc[k];
        v += __shfl_xor(v,1); v += __shfl_xor(v,2);
        v += __shfl_xor(v,4); v += __shfl_xor(v,8);
        racc[k] = v;
    }
    if (ln == 0){
        #pragma unroll
        for (int mt=0;mt<4;mt++)
            #pragma unroll
            for (int rx=0;rx<4;rx++)
                rpart[wave][mt*16 + quad*4 + rx] = racc[mt*4+rx];
    }
    __syncthreads();
    if (tid < 64)
        r[(size_t)bg*HD + i0 + tid] = rpart[0][tid]+rpart[1][tid]+rpart[2][tid]+rpart[3][tid];
}

// ---------------- k_update: producer/consumer wave specialization (r4 body, (512,2)) ----------------
// 512 threads. Waves 0-3 (A): S-tile for i-step t, exp -> w, write LDS buf t&1.
// Waves 4-7 (B): consume w-tile t-1 from buf (t-1)&1, acc2 += qN * w.
// One barrier per iteration. Each SIMD hosts 1 A-wave + 1 B-wave: A's load/exp stalls
// overlap B's MFMA. (512,2): 256-reg budget -> no spill (r4's 64-reg split was the bug).
__global__ __launch_bounds__(512,2) void k_update(
    const u16* __restrict__ qTh, const u16* __restrict__ qTl,
    u16* zTh, u16* zTl,                               // read (A resident) then overwritten (B, own rows)
    const u16* __restrict__ qNh, const u16* __restrict__ qNl,
    const float* __restrict__ bias, const float* __restrict__ alpha,
    const float* __restrict__ r)
{
    const int bg = blockIdx.y, j0 = blockIdx.x*64;
    const int tid = threadIdx.x, wave = tid>>6, lane = tid&63, ln = lane&15, quad = lane>>4;
    const float a = alpha[0];
    __shared__ u16 wlh[2][64*128], wll[2][64*128];    // double-buffered w^T [j][i], swizzled
    __shared__ float denl[4][32];

    // A-wave state (waves 0-3): owns 64 i x 32 j of the S tile
    const int iA = (wave&1)*64, jA = (wave>>1)*32;
    s16x8 Bh[2][2], Bl[2][2];
    float bj[2] = {0.f, 0.f};
    float den[2] = {0.f, 0.f};
    // B-wave state (waves 4-7): owns 32 c x 32 j of the zeta_num tile
    const int vb = wave - 4;
    const int cm = (vb&1)*32, jn = (vb>>1)*32;
    f32x4 acc2[2][2] = {{z4(),z4()},{z4(),z4()}};

    if (wave < 4){
        #pragma unroll
        for (int nt=0;nt<2;nt++){
            #pragma unroll
            for (int ks=0;ks<2;ks++){
                size_t off = ((size_t)bg*HD + j0 + jA + nt*16 + ln)*CD + ks*32 + quad*8;
                Bh[nt][ks] = ld8(zTh + off);
                Bl[nt][ks] = ld8(zTl + off);
            }
            bj[nt] = bias[(size_t)bg*HD + j0 + jA + nt*16 + ln];
        }
    }

    for (int t=0; t<17; ++t){
        __syncthreads();
        if (wave < 4){
            if (t < 16){
                const int is = t*128;
                // r reciprocals for this step's 16 rows
                float ri[16];
                #pragma unroll
                for (int mt=0;mt<4;mt++){
                    float4 rv = *(const float4*)&r[(size_t)bg*HD + is + iA + mt*16 + quad*4];
                    ri[mt*4+0] = __builtin_amdgcn_rcpf(rv.x);
                    ri[mt*4+1] = __builtin_amdgcn_rcpf(rv.y);
                    ri[mt*4+2] = __builtin_amdgcn_rcpf(rv.z);
                    ri[mt*4+3] = __builtin_amdgcn_rcpf(rv.w);
                }
                f32x4 acc1[4][2];
                #pragma unroll
                for (int mt=0;mt<4;mt++){ acc1[mt][0]=z4(); acc1[mt][1]=z4(); }
                #pragma unroll
                for (int ks=0;ks<2;ks++){
                    s16x8 Ah[4], Al[4];
                    #pragma unroll
                    for (int mt=0;mt<4;mt++){
                        size_t off = ((size_t)bg*HD + is + iA + mt*16 + ln)*CD + ks*32 + quad*8;
                        Ah[mt] = ld8(qTh + off);
                        Al[mt] = ld8(qTl + off);
                    }
                    #pragma unroll
                    for (int mt=0;mt<4;mt++)
                        #pragma unroll
                        for (int nt=0;nt<2;nt++)
                            acc1[mt][nt] = mm3(Ah[mt], Al[mt], Bh[nt][ks], Bl[nt][ks], acc1[mt][nt]);
                }
                const int buf = t & 1;
                #pragma unroll
                for (int mt=0;mt<4;mt++)
                    #pragma unroll
                    for (int nt=0;nt<2;nt++){
                        u16 hh[4], ll[4];
                        #pragma unroll
                        for (int rx=0;rx<4;rx++){
                            float w = __expf(fmaf(a, acc1[mt][nt][rx], bj[nt])) * ri[mt*4+rx];
                            den[nt] += w;
                            split2(w, hh[rx], ll[rx]);
                        }
                        int row = jA + nt*16 + ln;                   // j-local
                        int c4  = iA + mt*16 + quad*4;               // i-local
                        int off = (row<<7) + ((((c4>>3) ^ (row&15))<<3) | (c4&7));
                        *(ushort4*)&wlh[buf][off] = make_ushort4(hh[0],hh[1],hh[2],hh[3]);
                        *(ushort4*)&wll[buf][off] = make_ushort4(ll[0],ll[1],ll[2],ll[3]);
                    }
            } else {
                // t==16: publish den partials (B consumes tile 15 concurrently)
                #pragma unroll
                for (int nt=0;nt<2;nt++){
                    float v = den[nt];
                    v += __shfl_xor(v,16); v += __shfl_xor(v,32);
                    if (quad == 0) denl[wave][nt*16 + ln] = v;
                }
            }
        } else {
            if (t >= 1){
                const int isp = (t-1)*128, buf = (t-1) & 1;
                #pragma unroll
                for (int ks2=0;ks2<4;ks2++){
                    s16x8 A2h[2], A2l[2], B2h[2], B2l[2];
                    #pragma unroll
                    for (int mtN=0;mtN<2;mtN++){
                        size_t off = ((size_t)bg*CD + cm + mtN*16 + ln)*HD + isp + ks2*32 + quad*8;
                        A2h[mtN] = ld8(qNh + off);
                        A2l[mtN] = ld8(qNl + off);
                    }
                    #pragma unroll
                    for (int nt2=0;nt2<2;nt2++){
                        int jl = jn + nt2*16 + ln;
                        int ob = (jl<<7) + (((ks2*4+quad) ^ (jl&15))<<3);
                        B2h[nt2] = ld8(&wlh[buf][ob]);
                        B2l[nt2] = ld8(&wll[buf][ob]);
                    }
                    #pragma unroll
                    for (int mtN=0;mtN<2;mtN++)
                        #pragma unroll
                        for (int nt2=0;nt2<2;nt2++)
                            acc2[mtN][nt2] = mm3(A2h[mtN], A2l[mtN], B2h[nt2], B2l[nt2], acc2[mtN][nt2]);
                }
            }
        }
    }
    __syncthreads();
    if (wave >= 4){
        #pragma unroll
        for (int nt2=0;nt2<2;nt2++){
            int jl = jn + nt2*16 + ln, b = jl>>5, ix = jl&31;
            float dinv = __builtin_amdgcn_rcpf(denl[2*b][ix] + denl[2*b+1][ix]);
            #pragma unroll
            for (int mtN=0;mtN<2;mtN++){
                u16 hh[4], ll[4];
                #pragma unroll
                for (int rx=0;rx<4;rx++){
                    float v = acc2[mtN][nt2][rx] * dinv;
                    split2(v, hh[rx], ll[rx]);
                }
                size_t off = ((size_t)bg*HD + j0 + jl)*CD + cm + mtN*16 + quad*4;
                *(ushort4*)(zTh + off) = make_ushort4(hh[0],hh[1],hh[2],hh[3]);
                *(ushort4*)(zTl + off) = make_ushort4(ll[0],ll[1],ll[2],ll[3]);
            }
        }
    }
}

// ---------------- k_final: same producer/consumer structure, (512,2) ----------------
__global__ __launch_bounds__(512,2) void k_final(
    const u16* __restrict__ qTh, const u16* __restrict__ qTl,
    const u16* __restrict__ zTh, const u16* __restrict__ zTl,
    const u16* __restrict__ muh, const u16* __restrict__ mul_,
    const float* __restrict__ bias, const float* __restrict__ alpha,
    float* __restrict__ out)
{
    const int bg = blockIdx.y, i0 = blockIdx.x*64;
    const int tid = threadIdx.x, wave = tid>>6, lane = tid&63, ln = lane&15, quad = lane>>4;
    const float a = alpha[0];
    __shared__ u16 elh[2][64*128], ell[2][64*128];    // double-buffered e^T [i][j], swizzled
    __shared__ float rl2[4][32];

    // A-wave state: owns 64 j (within step) x 32 i
    const int jm = (wave&1)*64, inA = (wave>>1)*32;
    s16x8 Bh[2][2], Bl[2][2];
    float racc[2] = {0.f, 0.f};
    // B-wave state: owns 32 c x 32 i
    const int vb = wave - 4;
    const int cm = (vb&1)*32, inB = (vb>>1)*32;
    f32x4 acc2[2][2] = {{z4(),z4()},{z4(),z4()}};

    if (wave < 4){
        #pragma unroll
        for (int nt=0;nt<2;nt++)
            #pragma unroll
            for (int ks=0;ks<2;ks++){
                size_t off = ((size_t)bg*HD + i0 + inA + nt*16 + ln)*CD + ks*32 + quad*8;
                Bh[nt][ks] = ld8(qTh + off);
                Bl[nt][ks] = ld8(qTl + off);
            }
    }

    for (int t=0; t<17; ++t){
        __syncthreads();
        if (wave < 4){
            if (t < 16){
                const int js = t*128;
                float bj[16];
                #pragma unroll
                for (int mt=0;mt<4;mt++){
                    float4 bv = *(const float4*)&bias[(size_t)bg*HD + js + jm + mt*16 + quad*4];
                    bj[mt*4+0]=bv.x; bj[mt*4+1]=bv.y; bj[mt*4+2]=bv.z; bj[mt*4+3]=bv.w;
                }
                f32x4 acc1[4][2];
                #pragma unroll
                for (int mt=0;mt<4;mt++){ acc1[mt][0]=z4(); acc1[mt][1]=z4(); }
                #pragma unroll
                for (int ks=0;ks<2;ks++){
                    s16x8 Ah[4], Al[4];
                    #pragma unroll
                    for (int mt=0;mt<4;mt++){
                        size_t off = ((size_t)bg*HD + js + jm + mt*16 + ln)*CD + ks*32 + quad*8;
                        Ah[mt] = ld8(zTh + off);
                        Al[mt] = ld8(zTl + off);
                    }
                    #pragma unroll
                    for (int mt=0;mt<4;mt++)
                        #pragma unroll
                        for (int nt=0;nt<2;nt++)
                            acc1[mt][nt] = mm3(Ah[mt], Al[mt], Bh[nt][ks], Bl[nt][ks], acc1[mt][nt]);
                }
                const int buf = t & 1;
                #pragma unroll
                for (int mt=0;mt<4;mt++)
                    #pragma unroll
                    for (int nt=0;nt<2;nt++){
                        u16 hh[4], ll[4];
                        #pragma unroll
                        for (int rx=0;rx<4;rx++){
                            float e = __expf(fmaf(a, acc1[mt][nt][rx], bj[mt*4+rx]));
                            racc[nt] += e;
                            split2(e, hh[rx], ll[rx]);
                        }
                        int row = inA + nt*16 + ln;                  // i-local
                        int c4  = jm + mt*16 + quad*4;               // j-local
                        int off = (row<<7) + ((((c4>>3) ^ (row&15))<<3) | (c4&7));
                        *(ushort4*)&elh[buf][off] = make_ushort4(hh[0],hh[1],hh[2],hh[3]);
                        *(ushort4*)&ell[buf][off] = make_ushort4(ll[0],ll[1],ll[2],ll[3]);
                    }
            } else {
                #pragma unroll
                for (int nt=0;nt<2;nt++){
                    float v = racc[nt];
                    v += __shfl_xor(v,16); v += __shfl_xor(v,32);
                    if (quad == 0) rl2[wave][nt*16 + ln] = v;
                }
            }
        } else {
            if (t >= 1){
                const int jsp = (t-1)*128, buf = (t-1) & 1;
                #pragma unroll
                for (int ks2=0;ks2<4;ks2++){
                    s16x8 A2h[2], A2l[2], B2h[2], B2l[2];
                    #pragma unroll
                    for (int mtN=0;mtN<2;mtN++){
                        size_t off = ((size_t)bg*CD + cm + mtN*16 + ln)*HD + jsp + ks2*32 + quad*8;
                        A2h[mtN] = ld8(muh + off);
                        A2l[mtN] = ld8(mul_ + off);
                    }
                    #pragma unroll
                    for (int nt2=0;nt2<2;nt2++){
                        int il = inB + nt2*16 + ln;
                        int ob = (il<<7) + (((ks2*4+quad) ^ (il&15))<<3);
                        B2h[nt2] = ld8(&elh[buf][ob]);
                        B2l[nt2] = ld8(&ell[buf][ob]);
                    }
                    #pragma unroll
                    for (int mtN=0;mtN<2;mtN++)
                        #pragma unroll
                        for (int nt2=0;nt2<2;nt2++)
                            acc2[mtN][nt2] = mm3(A2h[mtN], A2l[mtN], B2h[nt2], B2l[nt2], acc2[mtN][nt2]);
                }
            }
        }
    }
    __syncthreads();
    if (wave >= 4){
        #pragma unroll
        for (int nt2=0;nt2<2;nt2++){
            int il = inB + nt2*16 + ln, b = il>>5, ix = il&31;
            float rinv = __builtin_amdgcn_rcpf(rl2[2*b][ix] + rl2[2*b+1][ix]);
            #pragma unroll
            for (int mtN=0;mtN<2;mtN++)
                #pragma unroll
                for (int rx=0;rx<4;rx++)
                    out[((size_t)bg*CD + cm + mtN*16 + quad*4 + rx)*HD + i0 + il]
                        = acc2[mtN][nt2][rx] * rinv;
        }
    }
}

extern "C" void kernel_launch(void* const* d_in, const int* in_sizes, int n_in,
                              void* d_out, int out_size, void* d_ws, size_t ws_size,
                              hipStream_t stream)
{
    (void)in_sizes; (void)n_in; (void)out_size; (void)ws_size;
    const float* q     = (const float*)d_in[0];
    const float* zeta  = (const float*)d_in[1];
    const float* alpha = (const float*)d_in[2];
    const float* mu    = (const float*)d_in[3];
    const float* beta  = (const float*)d_in[4];
    float* out = (float*)d_out;

    const size_t SZ = (size_t)NB*HD*CD;   // elements per tensor
    u16* qTh = (u16*)d_ws;
    u16* qTl = qTh + 1*SZ;
    u16* zTh = qTh + 2*SZ;
    u16* zTl = qTh + 3*SZ;
    u16* qNh = qTh + 4*SZ;
    u16* qNl = qTh + 5*SZ;
    u16* muh = qTh + 6*SZ;
    u16* mul_= qTh + 7*SZ;
    float* bias = (float*)(qTh + 8*SZ);
    float* r    = bias + (size_t)NB*HD;

    dim3 blk(256,1,1);
    dim3 blk5(512,1,1);
    int n4 = (int)(SZ/4);
    k_convert  <<<dim3(n4/256), blk, 0, stream>>>(q,  qNh, qNl, n4);
    k_convert  <<<dim3(n4/256), blk, 0, stream>>>(mu, muh, mul_, n4);
    k_transpose<<<dim3(HD/128, NB), blk, 0, stream>>>(q,    qTh, qTl);
    k_transpose<<<dim3(HD/128, NB), blk, 0, stream>>>(zeta, zTh, zTl);
    k_bias     <<<dim3(HD/256, NB), blk, 0, stream>>>(mu, beta, bias);

    k_rowsum<<<dim3(HD/64, NB), blk, 0, stream>>>(qTh,qTl,zTh,zTl,bias,alpha,r);
    k_update<<<dim3(HD/64, NB), blk5, 0, stream>>>(qTh,qTl,zTh,zTl,qNh,qNl,bias,alpha,r);
    k_rowsum<<<dim3(HD/64, NB), blk, 0, stream>>>(qTh,qTl,zTh,zTl,bias,alpha,r);
    k_update<<<dim3(HD/64, NB), blk5, 0, stream>>>(qTh,qTl,zTh,zTl,qNh,qNl,bias,alpha,r);
    k_final <<<dim3(HD/64, NB), blk5, 0, stream>>>(qTh,qTl,zTh,zTl,muh,mul_,bias,alpha,out);
}

// Round 12
// 466.543 us; speedup vs baseline: 1.3331x; 1.3331x over previous
//
#include <hip/hip_runtime.h>

#define NB 16    // N*G
#define CD 64    // C == Cv
#define HD 2048  // H

typedef unsigned short u16;
typedef __attribute__((ext_vector_type(8))) short s16x8;  // 8 bf16 (4 VGPRs)
typedef __attribute__((ext_vector_type(4))) float f32x4;  // MFMA C/D

__device__ __forceinline__ u16 f2bf(float x){
    unsigned u = __float_as_uint(x);
    u += 0x7FFFu + ((u >> 16) & 1u);   // RNE
    return (u16)(u >> 16);
}
__device__ __forceinline__ float bf2f(u16 h){ return __uint_as_float(((unsigned)h) << 16); }
__device__ __forceinline__ void split2(float x, u16& h, u16& l){
    h = f2bf(x); l = f2bf(x - bf2f(h));   // x - hi is exact in fp32
}
union Frag { uint4 q; s16x8 s; };
__device__ __forceinline__ s16x8 ld8(const u16* p){ Frag f; f.q = *(const uint4*)p; return f.s; }
__device__ __forceinline__ f32x4 mfma16(s16x8 a, s16x8 b, f32x4 c){
    return __builtin_amdgcn_mfma_f32_16x16x32_bf16(a, b, c, 0, 0, 0);
}
// fp32-emulating triple MFMA: hi*hi + hi*lo + lo*hi
__device__ __forceinline__ f32x4 mm3(s16x8 ah, s16x8 al, s16x8 bh, s16x8 bl, f32x4 c){
    c = mfma16(ah, bh, c);
    c = mfma16(ah, bl, c);
    c = mfma16(al, bh, c);
    return c;
}
__device__ __forceinline__ f32x4 z4(){ f32x4 v = {0.f,0.f,0.f,0.f}; return v; }

// XCD-aware swizzle (r10: FETCH 70->12 MB; keep). All blocks on one XCD share bg
// in {2*xcd, 2*xcd+1}; per-XCD L2 holds 2 bgs' sweep operands.
__device__ __forceinline__ void xcd_map(int& bg, int& tile){
    int lb = blockIdx.y*32 + blockIdx.x;
    int xcd = lb & 7, t = lb >> 3;
    bg = 2*xcd + (t >> 5);
    tile = t & 31;
}

// ---------------- prep kernels (unchanged) ----------------

__global__ void k_convert(const float* __restrict__ src, u16* __restrict__ dh,
                          u16* __restrict__ dl, int n4)
{
    int idx = blockIdx.x*256 + threadIdx.x;
    if (idx >= n4) return;
    float4 v = ((const float4*)src)[idx];
    ushort4 h, l;
    split2(v.x, h.x, l.x); split2(v.y, h.y, l.y);
    split2(v.z, h.z, l.z); split2(v.w, h.w, l.w);
    ((ushort4*)dh)[idx] = h;
    ((ushort4*)dl)[idx] = l;
}

__global__ void k_transpose(const float* __restrict__ src, u16* __restrict__ dh,
                            u16* __restrict__ dl)
{
    int bg = blockIdx.y, h0 = blockIdx.x*128, tid = threadIdx.x;
    __shared__ float ft[CD][132];
    #pragma unroll
    for (int k=0;k<8;k++){
        int flat = tid + 256*k;
        int c = flat >> 5, p = (flat & 31)*4;
        *(float4*)&ft[c][p] = *(const float4*)(src + ((size_t)bg*CD + c)*HD + h0 + p);
    }
    __syncthreads();
    int hl = tid >> 1, c0 = (tid & 1)*32;
    union { u16 u[32]; uint4 q[4]; } oh, ol;
    #pragma unroll
    for (int m=0;m<32;m++){
        float x = ft[c0+m][hl];
        u16 hh; split2(x, hh, ol.u[m]); oh.u[m] = hh;
    }
    size_t base = ((size_t)bg*HD + h0 + hl)*CD + c0;
    #pragma unroll
    for (int t=0;t<4;t++){
        *((uint4*)(dh + base) + t) = oh.q[t];
        *((uint4*)(dl + base) + t) = ol.q[t];
    }
}

__global__ void k_bias(const float* __restrict__ mu, const float* __restrict__ beta,
                       float* __restrict__ bias)
{
    int bg = blockIdx.y;
    int j  = blockIdx.x*256 + threadIdx.x;
    const float* m = mu + (size_t)bg*CD*HD + j;
    float s = 0.f;
    #pragma unroll
    for (int c=0;c<CD;c++){ float v = m[(size_t)c*HD]; s = fmaf(v, v, s); }
    bias[(size_t)bg*HD + j] = 0.5f * beta[0] * s;
}

// ---------------- main MFMA kernels ----------------

// r[i] = sum_j exp(a*S+bias_j). HI-ONLY bf16 S (single MFMA, no lo planes):
// r only normalizes w; per-row relative error (~0.1% softmax-weighted) scales all
// w in row i uniformly and cancels in zeta = sum w q / sum w to first order.
// 3x fewer MFMAs, 2x fewer operand loads than mm3.
__global__ __launch_bounds__(256,2) void k_rowsum(
    const u16* __restrict__ qTh, const u16* __restrict__ qTl,
    const u16* __restrict__ zTh, const u16* __restrict__ zTl,
    const float* __restrict__ bias, const float* __restrict__ alpha,
    float* __restrict__ r)
{
    int bg, itile; xcd_map(bg, itile);
    const int i0 = itile*64;
    const int tid = threadIdx.x, wave = tid>>6, lane = tid&63, ln = lane&15, quad = lane>>4;
    const int jw = wave*32;
    const float a = alpha[0];
    __shared__ float rpart[4][64];

    s16x8 Ah[4][2];               // resident q^T frags (hi only): rows i0..i0+63
    #pragma unroll
    for (int mt=0;mt<4;mt++)
        #pragma unroll
        for (int ks=0;ks<2;ks++){
            size_t off = ((size_t)bg*HD + i0 + mt*16 + ln)*CD + ks*32 + quad*8;
            Ah[mt][ks] = ld8(qTh + off);
        }
    float racc[16];
    #pragma unroll
    for (int k=0;k<16;k++) racc[k] = 0.f;
    const float* bb = bias + (size_t)bg*HD;

    s16x8 B0h[2][2], B1h[2][2];
    float bj0[2], bj1[2];

    // prologue: tile 0
    #pragma unroll
    for (int nt=0;nt<2;nt++){
        #pragma unroll
        for (int ks=0;ks<2;ks++){
            size_t off = ((size_t)bg*HD + jw + nt*16 + ln)*CD + ks*32 + quad*8;
            B0h[nt][ks] = ld8(zTh + off);
        }
        bj0[nt] = bb[jw + nt*16 + ln];
    }

    for (int j0=0;j0<HD;j0+=256){
        // issue loads for tile j0+128 into B1, pinned above the B0 compute
        #pragma unroll
        for (int nt=0;nt<2;nt++){
            #pragma unroll
            for (int ks=0;ks<2;ks++){
                size_t off = ((size_t)bg*HD + j0+128 + jw + nt*16 + ln)*CD + ks*32 + quad*8;
                B1h[nt][ks] = ld8(zTh + off);
            }
            bj1[nt] = bb[j0+128 + jw + nt*16 + ln];
        }
        __builtin_amdgcn_sched_barrier(0);
        // compute tile j0 with B0
        {
            f32x4 acc[4][2];
            #pragma unroll
            for (int mt=0;mt<4;mt++){ acc[mt][0]=z4(); acc[mt][1]=z4(); }
            __builtin_amdgcn_s_setprio(1);
            #pragma unroll
            for (int ks=0;ks<2;ks++)
                #pragma unroll
                for (int mt=0;mt<4;mt++)
                    #pragma unroll
                    for (int nt=0;nt<2;nt++)
                        acc[mt][nt] = mfma16(Ah[mt][ks], B0h[nt][ks], acc[mt][nt]);
            __builtin_amdgcn_s_setprio(0);
            #pragma unroll
            for (int mt=0;mt<4;mt++)
                #pragma unroll
                for (int nt=0;nt<2;nt++)
                    #pragma unroll
                    for (int rx=0;rx<4;rx++)
                        racc[mt*4+rx] += __expf(fmaf(a, acc[mt][nt][rx], bj0[nt]));
        }
        // issue loads for tile (j0+256)&(HD-1) into B0, pinned above the B1 compute
        {
            int jn2 = (j0+256) & (HD-1);
            #pragma unroll
            for (int nt=0;nt<2;nt++){
                #pragma unroll
                for (int ks=0;ks<2;ks++){
                    size_t off = ((size_t)bg*HD + jn2 + jw + nt*16 + ln)*CD + ks*32 + quad*8;
                    B0h[nt][ks] = ld8(zTh + off);
                }
                bj0[nt] = bb[jn2 + jw + nt*16 + ln];
            }
        }
        __builtin_amdgcn_sched_barrier(0);
        // compute tile j0+128 with B1
        {
            f32x4 acc[4][2];
            #pragma unroll
            for (int mt=0;mt<4;mt++){ acc[mt][0]=z4(); acc[mt][1]=z4(); }
            __builtin_amdgcn_s_setprio(1);
            #pragma unroll
            for (int ks=0;ks<2;ks++)
                #pragma unroll
                for (int mt=0;mt<4;mt++)
                    #pragma unroll
                    for (int nt=0;nt<2;nt++)
                        acc[mt][nt] = mfma16(Ah[mt][ks], B1h[nt][ks], acc[mt][nt]);
            __builtin_amdgcn_s_setprio(0);
            #pragma unroll
            for (int mt=0;mt<4;mt++)
                #pragma unroll
                for (int nt=0;nt<2;nt++)
                    #pragma unroll
                    for (int rx=0;rx<4;rx++)
                        racc[mt*4+rx] += __expf(fmaf(a, acc[mt][nt][rx], bj1[nt]));
        }
    }
    #pragma unroll
    for (int k=0;k<16;k++){
        float v = racc[k];
        v += __shfl_xor(v,1); v += __shfl_xor(v,2);
        v += __shfl_xor(v,4); v += __shfl_xor(v,8);
        racc[k] = v;
    }
    if (ln == 0){
        #pragma unroll
        for (int mt=0;mt<4;mt++)
            #pragma unroll
            for (int rx=0;rx<4;rx++)
                rpart[wave][mt*16 + quad*4 + rx] = racc[mt*4+rx];
    }
    __syncthreads();
    if (tid < 64)
        r[(size_t)bg*HD + i0 + tid] = rpart[0][tid]+rpart[1][tid]+rpart[2][tid]+rpart[3][tid];
}

// zeta update. Block: 64 j-cols, sweeps i (128/step). LDS w-tile double-buffered.
__global__ __launch_bounds__(256,2) void k_update(
    const u16* __restrict__ qTh, const u16* __restrict__ qTl,
    u16* zTh, u16* zTl,                               // read then overwritten (own rows only)
    const u16* __restrict__ qNh, const u16* __restrict__ qNl,
    const float* __restrict__ bias, const float* __restrict__ alpha,
    const float* __restrict__ r)
{
    int bg, jtile; xcd_map(bg, jtile);
    const int j0 = jtile*64;
    const int tid = threadIdx.x, wave = tid>>6, lane = tid&63, ln = lane&15, quad = lane>>4;
    const int cm = (wave&1)*32, jn = (wave>>1)*32;
    const float a = alpha[0];
    __shared__ u16 wlh[2][64*128], wll[2][64*128];    // double-buffered w^T [j][i], swizzled
    __shared__ float denl[4][64];

    s16x8 Bh[4][2], Bl[4][2];     // resident z^T frags: rows j0..j0+63 (read before any write)
    #pragma unroll
    for (int nt=0;nt<4;nt++)
        #pragma unroll
        for (int ks=0;ks<2;ks++){
            size_t off = ((size_t)bg*HD + j0 + nt*16 + ln)*CD + ks*32 + quad*8;
            Bh[nt][ks] = ld8(zTh + off);
            Bl[nt][ks] = ld8(zTl + off);
        }
    float bj[4];
    #pragma unroll
    for (int nt=0;nt<4;nt++) bj[nt] = bias[(size_t)bg*HD + j0 + nt*16 + ln];

    f32x4 acc2[2][2] = {{z4(),z4()},{z4(),z4()}};
    float den[4] = {0.f,0.f,0.f,0.f};
    int buf = 0;

    for (int is=0; is<HD; is+=128, buf^=1){
        // ---- issue phase-A operand loads (q^T) ----
        s16x8 Ah[2][2], Al[2][2];
        #pragma unroll
        for (int ks=0;ks<2;ks++)
            #pragma unroll
            for (int mt=0;mt<2;mt++){
                size_t off = ((size_t)bg*HD + is + wave*32 + mt*16 + ln)*CD + ks*32 + quad*8;
                Ah[mt][ks] = ld8(qTh + off);
                Al[mt][ks] = ld8(qTl + off);
            }
        // ---- issue ALL phase-B operand loads (qN) ----
        s16x8 A2h[4][2], A2l[4][2];
        #pragma unroll
        for (int ks2=0;ks2<4;ks2++)
            #pragma unroll
            for (int mtN=0;mtN<2;mtN++){
                size_t off = ((size_t)bg*CD + cm + mtN*16 + ln)*HD + is + ks2*32 + quad*8;
                A2h[ks2][mtN] = ld8(qNh + off);
                A2l[ks2][mtN] = ld8(qNl + off);
            }
        // ---- r loads (vectorized) ----
        float ri[8];
        #pragma unroll
        for (int mt=0;mt<2;mt++){
            float4 rv = *(const float4*)&r[(size_t)bg*HD + is + wave*32 + mt*16 + quad*4];
            ri[mt*4+0] = __builtin_amdgcn_rcpf(rv.x);
            ri[mt*4+1] = __builtin_amdgcn_rcpf(rv.y);
            ri[mt*4+2] = __builtin_amdgcn_rcpf(rv.z);
            ri[mt*4+3] = __builtin_amdgcn_rcpf(rv.w);
        }
        // PIN: no load above may sink below this point.
        __builtin_amdgcn_sched_barrier(0);
        // ---- phase A MFMA ----
        f32x4 acc1[2][4];
        #pragma unroll
        for (int mt=0;mt<2;mt++)
            #pragma unroll
            for (int nt=0;nt<4;nt++) acc1[mt][nt] = z4();
        __builtin_amdgcn_s_setprio(1);
        #pragma unroll
        for (int ks=0;ks<2;ks++)
            #pragma unroll
            for (int mt=0;mt<2;mt++)
                #pragma unroll
                for (int nt=0;nt<4;nt++)
                    acc1[mt][nt] = mm3(Ah[mt][ks], Al[mt][ks], Bh[nt][ks], Bl[nt][ks], acc1[mt][nt]);
        __builtin_amdgcn_s_setprio(0);
        // ---- w compute + LDS write (buffer `buf`) ----
        #pragma unroll
        for (int mt=0;mt<2;mt++)
            #pragma unroll
            for (int nt=0;nt<4;nt++){
                u16 hh[4], ll[4];
                #pragma unroll
                for (int rx=0;rx<4;rx++){
                    float w = __expf(fmaf(a, acc1[mt][nt][rx], bj[nt])) * ri[mt*4+rx];
                    den[nt] += w;
                    split2(w, hh[rx], ll[rx]);
                }
                int row = nt*16 + ln;                        // j-local
                int c4  = wave*32 + mt*16 + quad*4;          // i-local
                int off = (row<<7) + ((((c4>>3) ^ (row&15))<<3) | (c4&7));
                *(ushort4*)&wlh[buf][off] = make_ushort4(hh[0],hh[1],hh[2],hh[3]);
                *(ushort4*)&wll[buf][off] = make_ushort4(ll[0],ll[1],ll[2],ll[3]);
            }
        __syncthreads();
        // ---- phase B: LDS reads + MFMA (global operands already in regs) ----
        __builtin_amdgcn_s_setprio(1);
        #pragma unroll
        for (int ks2=0;ks2<4;ks2++){
            s16x8 B2h[2], B2l[2];
            #pragma unroll
            for (int nt2=0;nt2<2;nt2++){
                int jl = jn + nt2*16 + ln;
                int ob = (jl<<7) + (((ks2*4+quad) ^ (jl&15))<<3);
                B2h[nt2] = ld8(&wlh[buf][ob]);
                B2l[nt2] = ld8(&wll[buf][ob]);
            }
            #pragma unroll
            for (int mtN=0;mtN<2;mtN++)
                #pragma unroll
                for (int nt2=0;nt2<2;nt2++)
                    acc2[mtN][nt2] = mm3(A2h[ks2][mtN], A2l[ks2][mtN], B2h[nt2], B2l[nt2], acc2[mtN][nt2]);
        }
        __builtin_amdgcn_s_setprio(0);
    }
    // denominator reduce: quads via shfl, waves via LDS
    #pragma unroll
    for (int nt=0;nt<4;nt++){
        float v = den[nt];
        v += __shfl_xor(v,16); v += __shfl_xor(v,32);
        if (quad == 0) denl[wave][nt*16 + ln] = v;
    }
    __syncthreads();
    #pragma unroll
    for (int nt2=0;nt2<2;nt2++){
        int jl = jn + nt2*16 + ln;
        float dinv = __builtin_amdgcn_rcpf(denl[0][jl]+denl[1][jl]+denl[2][jl]+denl[3][jl]);
        #pragma unroll
        for (int mtN=0;mtN<2;mtN++){
            u16 hh[4], ll[4];
            #pragma unroll
            for (int rx=0;rx<4;rx++){
                float v = acc2[mtN][nt2][rx] * dinv;
                split2(v, hh[rx], ll[rx]);
            }
            size_t off = ((size_t)bg*HD + j0 + jl)*CD + cm + mtN*16 + quad*4;
            *(ushort4*)(zTh + off) = make_ushort4(hh[0],hh[1],hh[2],hh[3]);
            *(ushort4*)(zTl + off) = make_ushort4(ll[0],ll[1],ll[2],ll[3]);
        }
    }
}

// final: out[c][i] = (sum_j e_ij mu_cj) / (sum_j e_ij). Same structure.
__global__ __launch_bounds__(256,2) void k_final(
    const u16* __restrict__ qTh, const u16* __restrict__ qTl,
    const u16* __restrict__ zTh, const u16* __restrict__ zTl,
    const u16* __restrict__ muh, const u16* __restrict__ mul_,
    const float* __restrict__ bias, const float* __restrict__ alpha,
    float* __restrict__ out)
{
    int bg, itile; xcd_map(bg, itile);
    const int i0 = itile*64;
    const int tid = threadIdx.x, wave = tid>>6, lane = tid&63, ln = lane&15, quad = lane>>4;
    const int cm = (wave&1)*32, in_ = (wave>>1)*32;
    const float a = alpha[0];
    __shared__ u16 elh[2][64*128], ell[2][64*128];    // double-buffered e^T [i][j], swizzled
    __shared__ float rl2[4][64];

    s16x8 Bh[4][2], Bl[4][2];     // resident q^T frags: rows i0..i0+63 (n operand)
    #pragma unroll
    for (int nt=0;nt<4;nt++)
        #pragma unroll
        for (int ks=0;ks<2;ks++){
            size_t off = ((size_t)bg*HD + i0 + nt*16 + ln)*CD + ks*32 + quad*8;
            Bh[nt][ks] = ld8(qTh + off);
            Bl[nt][ks] = ld8(qTl + off);
        }
    f32x4 acc2[2][2] = {{z4(),z4()},{z4(),z4()}};
    float racc[4] = {0.f,0.f,0.f,0.f};
    int buf = 0;

    for (int js=0; js<HD; js+=128, buf^=1){
        // ---- issue phase-A operand loads (z^T) ----
        s16x8 Ah[2][2], Al[2][2];
        #pragma unroll
        for (int ks=0;ks<2;ks++)
            #pragma unroll
            for (int mt=0;mt<2;mt++){
                size_t off = ((size_t)bg*HD + js + wave*32 + mt*16 + ln)*CD + ks*32 + quad*8;
                Ah[mt][ks] = ld8(zTh + off);
                Al[mt][ks] = ld8(zTl + off);
            }
        // ---- issue ALL phase-B operand loads (mu) ----
        s16x8 A2h[4][2], A2l[4][2];
        #pragma unroll
        for (int ks2=0;ks2<4;ks2++)
            #pragma unroll
            for (int mtN=0;mtN<2;mtN++){
                size_t off = ((size_t)bg*CD + cm + mtN*16 + ln)*HD + js + ks2*32 + quad*8;
                A2h[ks2][mtN] = ld8(muh + off);
                A2l[ks2][mtN] = ld8(mul_ + off);
            }
        // ---- bias loads (vectorized) ----
        float bj8[8];
        #pragma unroll
        for (int mt=0;mt<2;mt++){
            float4 bv = *(const float4*)&bias[(size_t)bg*HD + js + wave*32 + mt*16 + quad*4];
            bj8[mt*4+0]=bv.x; bj8[mt*4+1]=bv.y; bj8[mt*4+2]=bv.z; bj8[mt*4+3]=bv.w;
        }
        // PIN: loads may not sink below.
        __builtin_amdgcn_sched_barrier(0);
        // ---- phase A MFMA: S'[j][i] (m = j, n = i) ----
        f32x4 acc1[2][4];
        #pragma unroll
        for (int mt=0;mt<2;mt++)
            #pragma unroll
            for (int nt=0;nt<4;nt++) acc1[mt][nt] = z4();
        __builtin_amdgcn_s_setprio(1);
        #pragma unroll
        for (int ks=0;ks<2;ks++)
            #pragma unroll
            for (int mt=0;mt<2;mt++)
                #pragma unroll
                for (int nt=0;nt<4;nt++)
                    acc1[mt][nt] = mm3(Ah[mt][ks], Al[mt][ks], Bh[nt][ks], Bl[nt][ks], acc1[mt][nt]);
        __builtin_amdgcn_s_setprio(0);
        // ---- e compute + LDS write (buffer `buf`) ----
        #pragma unroll
        for (int mt=0;mt<2;mt++)
            #pragma unroll
            for (int nt=0;nt<4;nt++){
                u16 hh[4], ll[4];
                #pragma unroll
                for (int rx=0;rx<4;rx++){
                    float e = __expf(fmaf(a, acc1[mt][nt][rx], bj8[mt*4+rx]));
                    racc[nt] += e;
                    split2(e, hh[rx], ll[rx]);
                }
                int row = nt*16 + ln;                        // i-local
                int c4  = wave*32 + mt*16 + quad*4;          // j-local
                int off = (row<<7) + ((((c4>>3) ^ (row&15))<<3) | (c4&7));
                *(ushort4*)&elh[buf][off] = make_ushort4(hh[0],hh[1],hh[2],hh[3]);
                *(ushort4*)&ell[buf][off] = make_ushort4(ll[0],ll[1],ll[2],ll[3]);
            }
        __syncthreads();
        // ---- phase B: acc2[c][i] += mu * e^T ----
        __builtin_amdgcn_s_setprio(1);
        #pragma unroll
        for (int ks2=0;ks2<4;ks2++){
            s16x8 B2h[2], B2l[2];
            #pragma unroll
            for (int nt2=0;nt2<2;nt2++){
                int il = in_ + nt2*16 + ln;
                int ob = (il<<7) + (((ks2*4+quad) ^ (il&15))<<3);
                B2h[nt2] = ld8(&elh[buf][ob]);
                B2l[nt2] = ld8(&ell[buf][ob]);
            }
            #pragma unroll
            for (int mtN=0;mtN<2;mtN++)
                #pragma unroll
                for (int nt2=0;nt2<2;nt2++)
                    acc2[mtN][nt2] = mm3(A2h[ks2][mtN], A2l[ks2][mtN], B2h[nt2], B2l[nt2], acc2[mtN][nt2]);
        }
        __builtin_amdgcn_s_setprio(0);
    }
    #pragma unroll
    for (int nt=0;nt<4;nt++){
        float v = racc[nt];
        v += __shfl_xor(v,16); v += __shfl_xor(v,32);
        if (quad == 0) rl2[wave][nt*16 + ln] = v;
    }
    __syncthreads();
    #pragma unroll
    for (int nt2=0;nt2<2;nt2++){
        int il = in_ + nt2*16 + ln;
        float rinv = __builtin_amdgcn_rcpf(rl2[0][il]+rl2[1][il]+rl2[2][il]+rl2[3][il]);
        #pragma unroll
        for (int mtN=0;mtN<2;mtN++)
            #pragma unroll
            for (int rx=0;rx<4;rx++)
                out[((size_t)bg*CD + cm + mtN*16 + quad*4 + rx)*HD + i0 + il]
                    = acc2[mtN][nt2][rx] * rinv;
    }
}

extern "C" void kernel_launch(void* const* d_in, const int* in_sizes, int n_in,
                              void* d_out, int out_size, void* d_ws, size_t ws_size,
                              hipStream_t stream)
{
    (void)in_sizes; (void)n_in; (void)out_size; (void)ws_size;
    const float* q     = (const float*)d_in[0];
    const float* zeta  = (const float*)d_in[1];
    const float* alpha = (const float*)d_in[2];
    const float* mu    = (const float*)d_in[3];
    const float* beta  = (const float*)d_in[4];
    float* out = (float*)d_out;

    const size_t SZ = (size_t)NB*HD*CD;   // elements per tensor
    u16* qTh = (u16*)d_ws;
    u16* qTl = qTh + 1*SZ;
    u16* zTh = qTh + 2*SZ;
    u16* zTl = qTh + 3*SZ;
    u16* qNh = qTh + 4*SZ;
    u16* qNl = qTh + 5*SZ;
    u16* muh = qTh + 6*SZ;
    u16* mul_= qTh + 7*SZ;
    float* bias = (float*)(qTh + 8*SZ);
    float* r    = bias + (size_t)NB*HD;

    dim3 blk(256,1,1);
    int n4 = (int)(SZ/4);
    k_convert  <<<dim3(n4/256), blk, 0, stream>>>(q,  qNh, qNl, n4);
    k_convert  <<<dim3(n4/256), blk, 0, stream>>>(mu, muh, mul_, n4);
    k_transpose<<<dim3(HD/128, NB), blk, 0, stream>>>(q,    qTh, qTl);
    k_transpose<<<dim3(HD/128, NB), blk, 0, stream>>>(zeta, zTh, zTl);
    k_bias     <<<dim3(HD/256, NB), blk, 0, stream>>>(mu, beta, bias);

    k_rowsum<<<dim3(HD/64, NB), blk, 0, stream>>>(qTh,qTl,zTh,zTl,bias,alpha,r);
    k_update<<<dim3(HD/64, NB), blk, 0, stream>>>(qTh,qTl,zTh,zTl,qNh,qNl,bias,alpha,r);
    k_rowsum<<<dim3(HD/64, NB), blk, 0, stream>>>(qTh,qTl,zTh,zTl,bias,alpha,r);
    k_update<<<dim3(HD/64, NB), blk, 0, stream>>>(qTh,qTl,zTh,zTl,qNh,qNl,bias,alpha,r);
    k_final <<<dim3(HD/64, NB), blk, 0, stream>>>(qTh,qTl,zTh,zTl,muh,mul_,bias,alpha,out);
}